// Round 10
// baseline (295.765 us; speedup 1.0000x reference)
//
#include <hip/hip_runtime.h>
#include <hip/hip_bf16.h>

#define BB 8
#define NN 16384
#define CC 128

typedef __attribute__((ext_vector_type(8))) short bf16x8;
typedef __attribute__((ext_vector_type(4))) short short4v;
typedef __attribute__((ext_vector_type(4))) float f32x4;

__device__ __forceinline__ unsigned short f2bf(float f) {
    union { float f; unsigned u; } v; v.f = f;
    unsigned r = v.u + 0x7fffu + ((v.u >> 16) & 1u);
    return (unsigned short)(r >> 16);
}
__device__ __forceinline__ float bf2f(unsigned short h) {
    union { unsigned u; float f; } v; v.u = ((unsigned)h) << 16;
    return v.f;
}
// truncating hi/lo split: lo captures the residual, RNE on hi unnecessary
__device__ __forceinline__ void split_trunc(float f, short& hi, short& lo) {
    union { float f; unsigned u; } v; v.f = f;
    const unsigned short hu = (unsigned short)(v.u >> 16);
    union { unsigned u; float f; } hf; hf.u = ((unsigned)hu) << 16;
    union { float f; unsigned u; } r; r.f = f - hf.f;
    hi = (short)hu;
    lo = (short)(r.u >> 16);
}

// ---------------------------------------------------------------------------
// W prep: split Wq/Wkv/Wproj into bf16 hi/lo (blocks 0-47); block 48
// precomputes sps[c] = 1/softplus(scale[c]). grid 49, block 256.
// ---------------------------------------------------------------------------
__global__ __launch_bounds__(256) void wprep_kernel(
    const float* __restrict__ Wq, const float* __restrict__ Wkv,
    const float* __restrict__ Wp, const float* __restrict__ scale,
    unsigned short* __restrict__ whi, unsigned short* __restrict__ wlo,
    float* __restrict__ sps)
{
    const int bid = blockIdx.x;
    if (bid == 48) {
        if (threadIdx.x < 128)
            sps[threadIdx.x] = 1.f / log1pf(expf(scale[threadIdx.x]));
        return;
    }
    const int mat = bid >> 4;
    const float* src = (mat == 0) ? Wq : ((mat == 1) ? Wkv : Wp);
    const int off = (bid & 15) * 1024 + threadIdx.x * 4;
    const float4 v = *(const float4*)(src + off);
    float f[4] = {v.x, v.y, v.z, v.w};
    short4v hv, lv;
#pragma unroll
    for (int j = 0; j < 4; ++j) {
        short h, lo2;
        split_trunc(f[j], h, lo2);
        hv[j] = h; lv[j] = lo2;
    }
    *(short4v*)(whi + mat * 16384 + off) = hv;
    *(short4v*)(wlo + mat * 16384 + off) = lv;
}

// ---------------------------------------------------------------------------
// qk v5: 64-token tiles, 4 waves x 16 tokens — R9 showed v4 latency-bound
// (occupancy 10.7%, all pipes idle, VGPR 164+64agpr => 2 waves/SIMD, only
// 1024 blocks). Halving per-wave state (~130 regs) + doubling grid to 2048
// + single transpose sub-phase per pass raises resident waves ~2-3x.
// grid 2048, block 256.
// ---------------------------------------------------------------------------
__global__ __launch_bounds__(256, 2) void qk_mfma_kernel(
    const float* __restrict__ x, const unsigned short* __restrict__ whi,
    const unsigned short* __restrict__ wlo, const float* __restrict__ w_g,
    const float* __restrict__ sps, const float* __restrict__ pos_enc,
    unsigned short* __restrict__ qout, unsigned short* __restrict__ kout,
    float* __restrict__ partial)
{
    __shared__ __align__(16) char smem[32768];   // 4 waves x 8KB transpose
    __shared__ float wpart[4][257];
    __shared__ float apl[64];

    const int tid  = threadIdx.x;
    const int w    = tid >> 6;
    const int l    = tid & 63;
    const int blk  = blockIdx.x;
    const int tok0 = blk * 64;
    const int tokb = (blk & 255) * 64;

    // ---- direct per-wave fragment loads: fp32 -> hi/lo bf16 in-register ----
    bf16x8 xh[4], xl[4];
    {
        const int r = w * 16 + (l & 15);
        const float* rowp = x + (tok0 + r) * 128 + (l >> 4) * 8;
#pragma unroll
        for (int kt = 0; kt < 4; ++kt) {
            const f32x4 a = *(const f32x4*)(rowp + kt * 32);
            const f32x4 b = *(const f32x4*)(rowp + kt * 32 + 4);
            const float f[8] = {a[0], a[1], a[2], a[3], b[0], b[1], b[2], b[3]};
            bf16x8 hv, lv;
#pragma unroll
            for (int j = 0; j < 8; ++j) {
                short h, lo2;
                split_trunc(f[j], h, lo2);
                hv[j] = h; lv[j] = lo2;
            }
            xh[kt] = hv; xl[kt] = lv;
        }
    }

    const int crow = (l >> 4) * 4;
    f32x4 acc[8];

    // =================== q pass ===================
#pragma unroll
    for (int m = 0; m < 8; ++m) acc[m] = (f32x4)0.f;
#pragma unroll
    for (int m = 0; m < 8; ++m) {
        const int c = m * 16 + (l & 15);
        bf16x8 ah[4], al[4];
#pragma unroll
        for (int kt = 0; kt < 4; ++kt) {
            const int off = c * 128 + kt * 32 + (l >> 4) * 8;
            ah[kt] = *(const bf16x8*)(whi + off);
            al[kt] = *(const bf16x8*)(wlo + off);
        }
#pragma unroll
        for (int kt = 0; kt < 4; ++kt) {
            acc[m] = __builtin_amdgcn_mfma_f32_16x16x32_bf16(ah[kt], xh[kt], acc[m], 0, 0, 0);
            acc[m] = __builtin_amdgcn_mfma_f32_16x16x32_bf16(ah[kt], xl[kt], acc[m], 0, 0, 0);
            acc[m] = __builtin_amdgcn_mfma_f32_16x16x32_bf16(al[kt], xh[kt], acc[m], 0, 0, 0);
        }
    }

    // ---- q epilogue ----
    {
#pragma unroll
        for (int m = 0; m < 8; ++m) {
            const float4 is4 = *(const float4*)(sps + m * 16 + crow);
            const float is[4] = {is4.x, is4.y, is4.z, is4.w};
#pragma unroll
            for (int j = 0; j < 4; ++j)
                acc[m][j] = (fmaxf(acc[m][j], 0.f) + 1e-6f) * is[j];
        }
        float s2 = 0.f, s6 = 0.f;
#pragma unroll
        for (int m = 0; m < 8; ++m)
#pragma unroll
            for (int j = 0; j < 4; ++j) {
                const float v = acc[m][j], v2 = v * v;
                s2 += v2; s6 += v2 * v2 * v2;
            }
        s2 += __shfl_xor(s2, 16); s6 += __shfl_xor(s6, 16);
        s2 += __shfl_xor(s2, 32); s6 += __shfl_xor(s6, 32);
        const float fq = sqrtf(s2 / s6);
#pragma unroll
        for (int m = 0; m < 8; ++m)
#pragma unroll
            for (int j = 0; j < 4; ++j) {
                const float v = acc[m][j];
                acc[m][j] = v * v * v * fq;
            }
        float d0 = 0.f;
#pragma unroll
        for (int m = 0; m < 8; ++m) {
            const float4 wgv = *(const float4*)(w_g + m * 16 + crow);
            d0 += acc[m][0] * wgv.x + acc[m][1] * wgv.y +
                  acc[m][2] * wgv.z + acc[m][3] * wgv.w;
        }
        d0 += __shfl_xor(d0, 16); d0 += __shfl_xor(d0, 32);
        const float ap = 0.25f * d0;

        float ssa = ap * ap;
        ssa += __shfl_xor(ssa, 1); ssa += __shfl_xor(ssa, 2);
        ssa += __shfl_xor(ssa, 4); ssa += __shfl_xor(ssa, 8);
        if (l == 0) wpart[w][256] = ssa;
        if (l < 16) apl[w * 16 + l] = ap;

        // transpose via wave-private 8KB, single 16-token phase
        const int t = l & 15;
        const int rb = w * 8192 + t * 512;
#pragma unroll
        for (int m = 0; m < 8; ++m) {
            const int ad = rb + (((m * 16 + crow) * 4) ^ ((t & 7) << 4));
            *(f32x4*)(smem + ad) = acc[m];
        }
        asm volatile("s_waitcnt lgkmcnt(0)" ::: "memory");
        float g4[4] = {0.f, 0.f, 0.f, 0.f};
#pragma unroll
        for (int j = 0; j < 8; ++j) {
            const int fid = j * 64 + l;
            const int row = fid >> 5;          // 0..15
            const int c4  = fid & 31;          // = l & 31
            const int rb3 = w * 8192 + row * 512;
            const f32x4 v = *(f32x4*)(smem + rb3 + ((c4 * 16) ^ ((row & 7) << 4)));
            const float apv = apl[w * 16 + row];
            short4v qv;
#pragma unroll
            for (int i = 0; i < 4; ++i) {
                g4[i] += apv * v[i];
                qv[i] = (short)f2bf(v[i]);
            }
            *(short4v*)(qout + (tok0 + w * 16 + row) * 128 + c4 * 4) = qv;
        }
#pragma unroll
        for (int i = 0; i < 4; ++i) g4[i] += __shfl_xor(g4[i], 32);
        if (l < 32) {
#pragma unroll
            for (int i = 0; i < 4; ++i) wpart[w][(l & 31) * 4 + i] = g4[i];
        }
    }

    // =================== k pass ===================
#pragma unroll
    for (int m = 0; m < 8; ++m) acc[m] = (f32x4)0.f;
#pragma unroll
    for (int m = 0; m < 8; ++m) {
        const int c = m * 16 + (l & 15);
        bf16x8 ah[4], al[4];
#pragma unroll
        for (int kt = 0; kt < 4; ++kt) {
            const int off = 16384 + c * 128 + kt * 32 + (l >> 4) * 8;
            ah[kt] = *(const bf16x8*)(whi + off);
            al[kt] = *(const bf16x8*)(wlo + off);
        }
#pragma unroll
        for (int kt = 0; kt < 4; ++kt) {
            acc[m] = __builtin_amdgcn_mfma_f32_16x16x32_bf16(ah[kt], xh[kt], acc[m], 0, 0, 0);
            acc[m] = __builtin_amdgcn_mfma_f32_16x16x32_bf16(ah[kt], xl[kt], acc[m], 0, 0, 0);
            acc[m] = __builtin_amdgcn_mfma_f32_16x16x32_bf16(al[kt], xh[kt], acc[m], 0, 0, 0);
        }
    }

    // ---- k epilogue ----
    {
        const int t = l & 15;
#pragma unroll
        for (int m = 0; m < 8; ++m) {
            const float4 is4 = *(const float4*)(sps + m * 16 + crow);
            const float is[4] = {is4.x, is4.y, is4.z, is4.w};
            const float4 p = *(const float4*)(pos_enc + (tokb + w * 16 + t) * 128 + m * 16 + crow);
            const float pe[4] = {p.x, p.y, p.z, p.w};
#pragma unroll
            for (int j = 0; j < 4; ++j)
                acc[m][j] = (fmaxf(acc[m][j] + pe[j], 0.f) + 1e-6f) * is[j];
        }
        float s2 = 0.f, s6 = 0.f;
#pragma unroll
        for (int m = 0; m < 8; ++m)
#pragma unroll
            for (int j = 0; j < 4; ++j) {
                const float v = acc[m][j], v2 = v * v;
                s2 += v2; s6 += v2 * v2 * v2;
            }
        s2 += __shfl_xor(s2, 16); s6 += __shfl_xor(s6, 16);
        s2 += __shfl_xor(s2, 32); s6 += __shfl_xor(s6, 32);
        const float fk = sqrtf(s2 / s6);
#pragma unroll
        for (int m = 0; m < 8; ++m)
#pragma unroll
            for (int j = 0; j < 4; ++j) {
                const float v = acc[m][j];
                acc[m][j] = v * v * v * fk;
            }
        const int rb = w * 8192 + t * 512;
#pragma unroll
        for (int m = 0; m < 8; ++m) {
            const int ad = rb + (((m * 16 + crow) * 4) ^ ((t & 7) << 4));
            *(f32x4*)(smem + ad) = acc[m];
        }
        asm volatile("s_waitcnt lgkmcnt(0)" ::: "memory");
        float ks4[4] = {0.f, 0.f, 0.f, 0.f};
#pragma unroll
        for (int j = 0; j < 8; ++j) {
            const int fid = j * 64 + l;
            const int row = fid >> 5;
            const int c4  = fid & 31;
            const int rb3 = w * 8192 + row * 512;
            const f32x4 v = *(f32x4*)(smem + rb3 + ((c4 * 16) ^ ((row & 7) << 4)));
            short4v kv;
#pragma unroll
            for (int i = 0; i < 4; ++i) {
                ks4[i] += v[i];
                kv[i] = (short)f2bf(v[i]);
            }
            *(short4v*)(kout + (tok0 + w * 16 + row) * 128 + c4 * 4) = kv;
        }
#pragma unroll
        for (int i = 0; i < 4; ++i) ks4[i] += __shfl_xor(ks4[i], 32);
        if (l < 32) {
#pragma unroll
            for (int i = 0; i < 4; ++i) wpart[w][128 + (l & 31) * 4 + i] = ks4[i];
        }
    }

    __syncthreads();
    float* pblk = partial + blk * 257;
    if (tid < 128) {
        pblk[tid] = wpart[0][tid] + wpart[1][tid] + wpart[2][tid] + wpart[3][tid];
        pblk[128 + tid] = wpart[0][128 + tid] + wpart[1][128 + tid] +
                          wpart[2][128 + tid] + wpart[3][128 + tid];
    } else if (tid == 128) {
        pblk[256] = wpart[0][256] + wpart[1][256] + wpart[2][256] + wpart[3][256];
    }
}

// ---------------------------------------------------------------------------
// reduce partials -> G, kbar. grid 8, block 256. 256 tiles/batch.
// ---------------------------------------------------------------------------
__global__ __launch_bounds__(256) void reduce_kernel(
    const float* __restrict__ partial, float* __restrict__ G,
    float* __restrict__ kbar)
{
    const int b = blockIdx.x;
    const int tid = threadIdx.x;
    __shared__ float tmp[4];

    float ssa = partial[(b * 256 + tid) * 257 + 256];
#pragma unroll
    for (int o = 32; o >= 1; o >>= 1) ssa += __shfl_xor(ssa, o);
    if ((tid & 63) == 0) tmp[tid >> 6] = ssa;
    __syncthreads();
    const float anorm = fmaxf(sqrtf(tmp[0] + tmp[1] + tmp[2] + tmp[3]), 1e-12f);
    const float inv_a = 1.f / anorm;

    if (tid < 128) {
        float g = 0.f;
        for (int t = 0; t < 256; ++t)
            g += partial[(b * 256 + t) * 257 + tid];
        G[b * 128 + tid] = g * inv_a;
    } else {
        const int c2 = tid - 128;
        float s = 0.f;
        for (int t = 0; t < 256; ++t)
            s += partial[(b * 256 + t) * 257 + 128 + c2];
        kbar[b * 128 + c2] = s * (1.f / 16384.f);
    }
}

// ---------------------------------------------------------------------------
// scramble: z + gating + cube-transpose. q and k both bf16.
// grid 2048, block 256.
// ---------------------------------------------------------------------------
__global__ __launch_bounds__(256) void scramble_kernel(
    const unsigned short* __restrict__ q, const unsigned short* __restrict__ k,
    const float* __restrict__ G, const float* __restrict__ kbar,
    float* __restrict__ out)
{
    __shared__ float u[64 * 129];
    const int tid  = threadIdx.x;
    const int bid  = blockIdx.x;
    const int half = bid & 1;
    const int r    = (bid >> 1) & 127;
    const int b    = bid >> 8;

    const int t  = tid >> 2;
    const int qt = tid & 3;
    const int tok   = r * 128 + half * 64 + t;
    const int gbase = (b * NN + tok) * CC + qt * 32;
    const int cb    = b * CC + qt * 32;

    float4 kb4[8], g4[8];
    float qf[32], kf[32];
#pragma unroll
    for (int j = 0; j < 8; ++j) {
        const short4v q4 = *(const short4v*)(q + gbase + j * 4);
        const short4v k4 = *(const short4v*)(k + gbase + j * 4);
#pragma unroll
        for (int i = 0; i < 4; ++i) {
            qf[j * 4 + i] = bf2f((unsigned short)q4[i]);
            kf[j * 4 + i] = bf2f((unsigned short)k4[i]);
        }
        kb4[j] = *(const float4*)(kbar + cb + j * 4);
        g4[j]  = *(const float4*)(G + cb + j * 4);
    }
    float dot0 = 0.f, dot1 = 0.f;
#pragma unroll
    for (int j = 0; j < 4; ++j) {
        dot0 += qf[j * 4] * kb4[j].x + qf[j * 4 + 1] * kb4[j].y +
                qf[j * 4 + 2] * kb4[j].z + qf[j * 4 + 3] * kb4[j].w;
        dot1 += qf[16 + j * 4] * kb4[j + 4].x + qf[16 + j * 4 + 1] * kb4[j + 4].y +
                qf[16 + j * 4 + 2] * kb4[j + 4].z + qf[16 + j * 4 + 3] * kb4[j + 4].w;
    }
    const float z0 = 1.f / (dot0 + 1e-6f);
    const float z1 = 1.f / (dot1 + 1e-6f);

    float* ut = u + t * 129 + qt * 32;
#pragma unroll
    for (int j = 0; j < 8; ++j) {
        const float zz = (j < 4) ? z0 : z1;
#pragma unroll
        for (int i = 0; i < 4; ++i) {
            const float gv = (i == 0) ? g4[j].x : (i == 1) ? g4[j].y : (i == 2) ? g4[j].z : g4[j].w;
            ut[j * 4 + i] = gv * kf[j * 4 + i] * zz;
        }
    }
    __syncthreads();

    const int obase = b * NN * CC + half * 64;
#pragma unroll
    for (int it = 0; it < 32; ++it) {
        const int idx = tid + it * 256;
        const int cc  = idx >> 6;
        const int ch  = idx & 63;
        out[obase + (cc * 128 + r) * CC + ch] = u[ch * 129 + cc];
    }
}

// ---------------------------------------------------------------------------
// convproj: fused depthwise 5x5 conv (bf16 k) + projection, in-place on out.
// Batch-per-XCD swizzle. grid 1024, block 256.
// ---------------------------------------------------------------------------
__global__ __launch_bounds__(256, 2) void convproj_kernel(
    float* __restrict__ out, const unsigned short* __restrict__ kbuf,
    const unsigned short* __restrict__ whi, const unsigned short* __restrict__ wlo,
    const float* __restrict__ bp, const float* __restrict__ dwc_w,
    const float* __restrict__ dwc_b)
{
    __shared__ __align__(16) char smem[65536];   // tile hi [0,32K), lo [32K,64K)
    __shared__ float wct[25][16];
    __shared__ float bi[16];

    const int tid  = threadIdx.x;
    const int bid0 = blockIdx.x;
    const int bid  = (bid0 & 7) * 128 + (bid0 >> 3);   // bijective XCD swizzle
    const int cc   = bid & 127;
    const int b    = bid >> 7;
    const int n0   = bid * 128;

    for (int i = tid; i < 400; i += 256)
        wct[i >> 4][i & 15] = dwc_w[(i & 15) * 25 + (i >> 4)];
    if (tid < 16) bi[tid] = dwc_b[tid];
    __syncthreads();

    const int l  = tid & 31;
    const int xg = tid >> 5;
    const int dbase = (l & 3) * 4;

    float4 acc[16];
#pragma unroll
    for (int i = 0; i < 16; ++i) acc[i] = make_float4(0.f, 0.f, 0.f, 0.f);

#pragma unroll
    for (int dy = 0; dy < 5; ++dy) {
        const int yy = cc + dy - 2;
        if (yy < 0 || yy > 127) continue;
        const unsigned short* rowb = kbuf + (b * NN + yy * 128) * CC + l * 4;
        float4 rowv[20];
#pragma unroll
        for (int xi = 0; xi < 20; ++xi) {
            const int xx = xg * 16 - 2 + xi;
            if (xx >= 0 && xx < 128) {
                const short4v kv4 = *(const short4v*)(rowb + xx * CC);
                rowv[xi] = make_float4(bf2f((unsigned short)kv4[0]),
                                       bf2f((unsigned short)kv4[1]),
                                       bf2f((unsigned short)kv4[2]),
                                       bf2f((unsigned short)kv4[3]));
            } else {
                rowv[xi] = make_float4(0.f, 0.f, 0.f, 0.f);
            }
        }
#pragma unroll
        for (int dx = 0; dx < 5; ++dx) {
            const float4 wv = *(const float4*)(&wct[dy * 5 + dx][dbase]);
#pragma unroll
            for (int i = 0; i < 16; ++i) {
                acc[i].x += wv.x * rowv[i + dx].x;
                acc[i].y += wv.y * rowv[i + dx].y;
                acc[i].z += wv.z * rowv[i + dx].z;
                acc[i].w += wv.w * rowv[i + dx].w;
            }
        }
    }

    const float4 b4 = *(const float4*)(&bi[dbase]);
#pragma unroll
    for (int i = 0; i < 16; ++i) {
        const int r = xg * 16 + i;
        const float4 pp = *(const float4*)(out + (n0 + r) * 128 + l * 4);
        float f[4] = {pp.x + acc[i].x + b4.x, pp.y + acc[i].y + b4.y,
                      pp.z + acc[i].z + b4.z, pp.w + acc[i].w + b4.w};
        short4v hv, lv;
#pragma unroll
        for (int j = 0; j < 4; ++j) {
            short h, lo2;
            split_trunc(f[j], h, lo2);
            hv[j] = h; lv[j] = lo2;
        }
        const int ad = r * 256 + (((l >> 1) * 16) ^ ((r & 7) << 4)) + (l & 1) * 8;
        *(short4v*)(smem + ad) = hv;
        *(short4v*)(smem + 32768 + ad) = lv;
    }
    __syncthreads();

    const int w  = tid >> 6;
    const int ll = tid & 63;
    bf16x8 xh[2][4], xl[2][4];
    {
        const int lg16 = (ll >> 4) * 16;
#pragma unroll
        for (int n = 0; n < 2; ++n) {
            const int r = w * 32 + n * 16 + (ll & 15);
            const int rb = r * 256;
            const int sw = (r & 7) << 4;
#pragma unroll
            for (int kt = 0; kt < 4; ++kt) {
                const int ad = rb + ((kt * 64 + lg16) ^ sw);
                xh[n][kt] = *(bf16x8*)(smem + ad);
                xl[n][kt] = *(bf16x8*)(smem + 32768 + ad);
            }
        }
    }
    const int crow = (ll >> 4) * 4;
    f32x4 pacc[8][2];
#pragma unroll
    for (int m = 0; m < 8; ++m)
#pragma unroll
        for (int n = 0; n < 2; ++n) pacc[m][n] = (f32x4)0.f;

#pragma unroll
    for (int m = 0; m < 8; ++m) {
        const int c = m * 16 + (ll & 15);
        bf16x8 ah[4], al[4];
#pragma unroll
        for (int kt = 0; kt < 4; ++kt) {
            const int off = 32768 + c * 128 + kt * 32 + (ll >> 4) * 8;
            ah[kt] = *(const bf16x8*)(whi + off);
            al[kt] = *(const bf16x8*)(wlo + off);
        }
#pragma unroll
        for (int n = 0; n < 2; ++n)
#pragma unroll
            for (int kt = 0; kt < 4; ++kt) {
                pacc[m][n] = __builtin_amdgcn_mfma_f32_16x16x32_bf16(ah[kt], xh[n][kt], pacc[m][n], 0, 0, 0);
                pacc[m][n] = __builtin_amdgcn_mfma_f32_16x16x32_bf16(ah[kt], xl[n][kt], pacc[m][n], 0, 0, 0);
                pacc[m][n] = __builtin_amdgcn_mfma_f32_16x16x32_bf16(al[kt], xh[n][kt], pacc[m][n], 0, 0, 0);
            }
    }

#pragma unroll
    for (int m = 0; m < 8; ++m) {
        const float4 bv = *(const float4*)(bp + m * 16 + crow);
        const float bb[4] = {bv.x, bv.y, bv.z, bv.w};
#pragma unroll
        for (int n = 0; n < 2; ++n)
#pragma unroll
            for (int j = 0; j < 4; ++j) pacc[m][n][j] += bb[j];
    }
    __syncthreads();
#pragma unroll
    for (int n = 0; n < 2; ++n) {
        const int t = n * 16 + (ll & 15);
        const int rb = w * 8192 + (t & 15) * 512 + ((t >= 16) ? 32768 : 0);
#pragma unroll
        for (int m = 0; m < 8; ++m) {
            const int ad = rb + (((m * 16 + crow) * 4) ^ ((t & 7) << 4));
            *(f32x4*)(smem + ad) = pacc[m][n];
        }
    }
    asm volatile("s_waitcnt lgkmcnt(0)" ::: "memory");
#pragma unroll
    for (int j = 0; j < 16; ++j) {
        const int fid = j * 64 + ll;
        const int row = fid >> 5;
        const int c4 = fid & 31;
        const int rb = w * 8192 + (row & 15) * 512 + ((row >= 16) ? 32768 : 0);
        const f32x4 v = *(f32x4*)(smem + rb + ((c4 * 16) ^ ((row & 7) << 4)));
        *(f32x4*)(out + (n0 + w * 32 + row) * 128 + c4 * 4) = v;
    }
}

// ---------------------------------------------------------------------------
extern "C" void kernel_launch(void* const* d_in, const int* in_sizes, int n_in,
                              void* d_out, int out_size, void* d_ws, size_t ws_size,
                              hipStream_t stream)
{
    const float* x       = (const float*)d_in[0];
    const float* Wq      = (const float*)d_in[1];
    const float* Wkv     = (const float*)d_in[2];
    const float* Wproj   = (const float*)d_in[3];
    const float* bproj   = (const float*)d_in[4];
    const float* w_g     = (const float*)d_in[5];
    const float* scale   = (const float*)d_in[6];
    const float* pos_enc = (const float*)d_in[7];
    const float* dwc_w   = (const float*)d_in[8];
    const float* dwc_b   = (const float*)d_in[9];
    float* out = (float*)d_out;

    char* ws = (char*)d_ws;
    unsigned short* qbuf = (unsigned short*)(ws);             // 33554432 B
    unsigned short* kbuf = (unsigned short*)(ws + 33554432);  // 33554432 B
    float* partial = (float*)(ws + 67108864);                 // 2048*257*4 = 2105344 B
    float* G       = (float*)(ws + 69214208);                 // 4096 B
    float* kbar    = (float*)(ws + 69218304);                 // 4096 B
    unsigned short* whi = (unsigned short*)(ws + 69222400);   // 98304 B
    unsigned short* wlo = (unsigned short*)(ws + 69320704);   // 98304 B
    float* sps     = (float*)(ws + 69419008);                 // 512 B

    wprep_kernel<<<dim3(49), dim3(256), 0, stream>>>(
        Wq, Wkv, Wproj, scale, whi, wlo, sps);
    qk_mfma_kernel<<<dim3(2048), dim3(256), 0, stream>>>(
        x, whi, wlo, w_g, sps, pos_enc, qbuf, kbuf, partial);
    reduce_kernel<<<dim3(8), dim3(256), 0, stream>>>(partial, G, kbar);
    scramble_kernel<<<dim3(2048), dim3(256), 0, stream>>>(
        qbuf, kbuf, G, kbar, out);
    convproj_kernel<<<dim3(1024), dim3(256), 0, stream>>>(
        out, kbuf, whi, wlo, bproj, dwc_w, dwc_b);
}

// Round 11
// 227.907 us; speedup vs baseline: 1.2977x; 1.2977x over previous
//
#include <hip/hip_runtime.h>
#include <hip/hip_bf16.h>

#define BB 8
#define NN 16384
#define CC 128

typedef __attribute__((ext_vector_type(8))) short bf16x8;
typedef __attribute__((ext_vector_type(4))) short short4v;
typedef __attribute__((ext_vector_type(4))) float f32x4;

__device__ __forceinline__ unsigned short f2bf(float f) {
    union { float f; unsigned u; } v; v.f = f;
    unsigned r = v.u + 0x7fffu + ((v.u >> 16) & 1u);
    return (unsigned short)(r >> 16);
}
__device__ __forceinline__ float bf2f(unsigned short h) {
    union { unsigned u; float f; } v; v.u = ((unsigned)h) << 16;
    return v.f;
}
// truncating hi/lo split: lo captures the residual, RNE on hi unnecessary
__device__ __forceinline__ void split_trunc(float f, short& hi, short& lo) {
    union { float f; unsigned u; } v; v.f = f;
    const unsigned short hu = (unsigned short)(v.u >> 16);
    union { unsigned u; float f; } hf; hf.u = ((unsigned)hu) << 16;
    union { float f; unsigned u; } r; r.f = f - hf.f;
    hi = (short)hu;
    lo = (short)(r.u >> 16);
}

// ---------------------------------------------------------------------------
// W prep: split Wq/Wkv/Wproj into bf16 hi/lo (blocks 0-47); block 48
// precomputes sps[c] = 1/softplus(scale[c]). grid 49, block 256.
// ---------------------------------------------------------------------------
__global__ __launch_bounds__(256) void wprep_kernel(
    const float* __restrict__ Wq, const float* __restrict__ Wkv,
    const float* __restrict__ Wp, const float* __restrict__ scale,
    unsigned short* __restrict__ whi, unsigned short* __restrict__ wlo,
    float* __restrict__ sps)
{
    const int bid = blockIdx.x;
    if (bid == 48) {
        if (threadIdx.x < 128)
            sps[threadIdx.x] = 1.f / log1pf(expf(scale[threadIdx.x]));
        return;
    }
    const int mat = bid >> 4;
    const float* src = (mat == 0) ? Wq : ((mat == 1) ? Wkv : Wp);
    const int off = (bid & 15) * 1024 + threadIdx.x * 4;
    const float4 v = *(const float4*)(src + off);
    float f[4] = {v.x, v.y, v.z, v.w};
    short4v hv, lv;
#pragma unroll
    for (int j = 0; j < 4; ++j) {
        short h, lo2;
        split_trunc(f[j], h, lo2);
        hv[j] = h; lv[j] = lo2;
    }
    *(short4v*)(whi + mat * 16384 + off) = hv;
    *(short4v*)(wlo + mat * 16384 + off) = lv;
}

// ---------------------------------------------------------------------------
// qk v6: 128-token tiles (R9 structure — best measured at 114us), with the
// q and k MFMA passes FUSED in one m-loop: per m, load Wq+Wk fragments then
// issue 48 independent MFMAs across two accumulator sets. R10 proved
// occupancy-chasing regresses (W amortization halves); R9's counters showed
// per-wave serialization — this doubles per-wave ILP so the MFMA work of m
// covers the L2 latency of m+1's loads. (256,1): live state ~290 regs,
// 1 wave/SIMD, no spill (tripwire: WRITE_SIZE >> 67MB).
// grid 1024, block 256 (4 waves x 32 tokens).
// ---------------------------------------------------------------------------
__global__ __launch_bounds__(256, 1) void qk_mfma_kernel(
    const float* __restrict__ x, const unsigned short* __restrict__ whi,
    const unsigned short* __restrict__ wlo, const float* __restrict__ w_g,
    const float* __restrict__ sps, const float* __restrict__ pos_enc,
    unsigned short* __restrict__ qout, unsigned short* __restrict__ kout,
    float* __restrict__ partial)
{
    __shared__ __align__(16) char smem[32768];   // 4 waves x 8KB transpose
    __shared__ float wpart[4][257];
    __shared__ float apl[128];

    const int tid  = threadIdx.x;
    const int w    = tid >> 6;
    const int l    = tid & 63;
    const int blk  = blockIdx.x;
    const int tok0 = blk * 128;
    const int tokb = (blk & 127) * 128;

    // ---- direct per-wave fragment loads: fp32 -> hi/lo bf16 in-register ----
    bf16x8 xh[2][4], xl[2][4];
#pragma unroll
    for (int n = 0; n < 2; ++n) {
        const int r = w * 32 + n * 16 + (l & 15);
        const float* rowp = x + (tok0 + r) * 128 + (l >> 4) * 8;
#pragma unroll
        for (int kt = 0; kt < 4; ++kt) {
            const f32x4 a = *(const f32x4*)(rowp + kt * 32);
            const f32x4 b = *(const f32x4*)(rowp + kt * 32 + 4);
            const float f[8] = {a[0], a[1], a[2], a[3], b[0], b[1], b[2], b[3]};
            bf16x8 hv, lv;
#pragma unroll
            for (int j = 0; j < 8; ++j) {
                short h, lo2;
                split_trunc(f[j], h, lo2);
                hv[j] = h; lv[j] = lo2;
            }
            xh[n][kt] = hv; xl[n][kt] = lv;
        }
    }

    const int crow = (l >> 4) * 4;
    f32x4 accq[8][2], acck[8][2];
#pragma unroll
    for (int m = 0; m < 8; ++m)
#pragma unroll
        for (int n = 0; n < 2; ++n) { accq[m][n] = (f32x4)0.f; acck[m][n] = (f32x4)0.f; }

    // =================== fused q+k MFMA loop ===================
#pragma unroll
    for (int m = 0; m < 8; ++m) {
        const int c = m * 16 + (l & 15);
        bf16x8 aqh[4], aql[4], akh[4], akl[4];
#pragma unroll
        for (int kt = 0; kt < 4; ++kt) {
            const int off = c * 128 + kt * 32 + (l >> 4) * 8;
            aqh[kt] = *(const bf16x8*)(whi + off);
            aql[kt] = *(const bf16x8*)(wlo + off);
            akh[kt] = *(const bf16x8*)(whi + 16384 + off);
            akl[kt] = *(const bf16x8*)(wlo + 16384 + off);
        }
#pragma unroll
        for (int n = 0; n < 2; ++n)
#pragma unroll
            for (int kt = 0; kt < 4; ++kt) {
                accq[m][n] = __builtin_amdgcn_mfma_f32_16x16x32_bf16(aqh[kt], xh[n][kt], accq[m][n], 0, 0, 0);
                acck[m][n] = __builtin_amdgcn_mfma_f32_16x16x32_bf16(akh[kt], xh[n][kt], acck[m][n], 0, 0, 0);
                accq[m][n] = __builtin_amdgcn_mfma_f32_16x16x32_bf16(aqh[kt], xl[n][kt], accq[m][n], 0, 0, 0);
                acck[m][n] = __builtin_amdgcn_mfma_f32_16x16x32_bf16(akh[kt], xl[n][kt], acck[m][n], 0, 0, 0);
                accq[m][n] = __builtin_amdgcn_mfma_f32_16x16x32_bf16(aql[kt], xh[n][kt], accq[m][n], 0, 0, 0);
                acck[m][n] = __builtin_amdgcn_mfma_f32_16x16x32_bf16(akl[kt], xh[n][kt], acck[m][n], 0, 0, 0);
            }
    }

    // ---- q epilogue ----
    {
#pragma unroll
        for (int m = 0; m < 8; ++m) {
            const float4 is4 = *(const float4*)(sps + m * 16 + crow);
            const float is[4] = {is4.x, is4.y, is4.z, is4.w};
#pragma unroll
            for (int n = 0; n < 2; ++n)
#pragma unroll
                for (int j = 0; j < 4; ++j)
                    accq[m][n][j] = (fmaxf(accq[m][n][j], 0.f) + 1e-6f) * is[j];
        }
        float fqn[2];
#pragma unroll
        for (int n = 0; n < 2; ++n) {
            float s2 = 0.f, s6 = 0.f;
#pragma unroll
            for (int m = 0; m < 8; ++m)
#pragma unroll
                for (int j = 0; j < 4; ++j) {
                    const float v = accq[m][n][j], v2 = v * v;
                    s2 += v2; s6 += v2 * v2 * v2;
                }
            s2 += __shfl_xor(s2, 16); s6 += __shfl_xor(s6, 16);
            s2 += __shfl_xor(s2, 32); s6 += __shfl_xor(s6, 32);
            fqn[n] = sqrtf(s2 / s6);
        }
#pragma unroll
        for (int m = 0; m < 8; ++m)
#pragma unroll
            for (int n = 0; n < 2; ++n)
#pragma unroll
                for (int j = 0; j < 4; ++j) {
                    const float v = accq[m][n][j];
                    accq[m][n][j] = v * v * v * fqn[n];
                }
        float d0 = 0.f, d1 = 0.f;
#pragma unroll
        for (int m = 0; m < 8; ++m) {
            const float4 wgv = *(const float4*)(w_g + m * 16 + crow);
#pragma unroll
            for (int j = 0; j < 4; ++j) {
                const float wg = (j == 0) ? wgv.x : (j == 1) ? wgv.y : (j == 2) ? wgv.z : wgv.w;
                d0 += accq[m][0][j] * wg;
                d1 += accq[m][1][j] * wg;
            }
        }
        d0 += __shfl_xor(d0, 16); d0 += __shfl_xor(d0, 32);
        d1 += __shfl_xor(d1, 16); d1 += __shfl_xor(d1, 32);
        const float ap0 = 0.25f * d0, ap1 = 0.25f * d1;

        float ssa = ap0 * ap0 + ap1 * ap1;
        ssa += __shfl_xor(ssa, 1); ssa += __shfl_xor(ssa, 2);
        ssa += __shfl_xor(ssa, 4); ssa += __shfl_xor(ssa, 8);
        if (l == 0) wpart[w][256] = ssa;
        if (l < 16) { apl[w * 32 + l] = ap0; apl[w * 32 + 16 + l] = ap1; }

        // transpose via wave-private 8KB, two 16-token sub-phases
        float g4[4] = {0.f, 0.f, 0.f, 0.f};
#pragma unroll
        for (int n = 0; n < 2; ++n) {
            const int t = l & 15;
            const int rb = w * 8192 + t * 512;
#pragma unroll
            for (int m = 0; m < 8; ++m) {
                const int ad = rb + (((m * 16 + crow) * 4) ^ ((t & 7) << 4));
                *(f32x4*)(smem + ad) = accq[m][n];
            }
            asm volatile("s_waitcnt lgkmcnt(0)" ::: "memory");
#pragma unroll
            for (int j = 0; j < 8; ++j) {
                const int fid = j * 64 + l;
                const int row = fid >> 5;
                const int c4  = fid & 31;
                const int rb3 = w * 8192 + row * 512;
                const f32x4 v = *(f32x4*)(smem + rb3 + ((c4 * 16) ^ ((row & 7) << 4)));
                const float apv = apl[w * 32 + n * 16 + row];
                short4v qv;
#pragma unroll
                for (int i = 0; i < 4; ++i) {
                    g4[i] += apv * v[i];
                    qv[i] = (short)f2bf(v[i]);
                }
                *(short4v*)(qout + (tok0 + w * 32 + n * 16 + row) * 128 + c4 * 4) = qv;
            }
        }
#pragma unroll
        for (int i = 0; i < 4; ++i) g4[i] += __shfl_xor(g4[i], 32);
        if (l < 32) {
#pragma unroll
            for (int i = 0; i < 4; ++i) wpart[w][(l & 31) * 4 + i] = g4[i];
        }
    }

    // ---- k epilogue ----
    {
#pragma unroll
        for (int m = 0; m < 8; ++m) {
            const float4 is4 = *(const float4*)(sps + m * 16 + crow);
            const float is[4] = {is4.x, is4.y, is4.z, is4.w};
#pragma unroll
            for (int n = 0; n < 2; ++n) {
                const int t = tokb + w * 32 + n * 16 + (l & 15);
                const float4 p = *(const float4*)(pos_enc + t * 128 + m * 16 + crow);
                const float pe[4] = {p.x, p.y, p.z, p.w};
#pragma unroll
                for (int j = 0; j < 4; ++j)
                    acck[m][n][j] = (fmaxf(acck[m][n][j] + pe[j], 0.f) + 1e-6f) * is[j];
            }
        }
        float fkn[2];
#pragma unroll
        for (int n = 0; n < 2; ++n) {
            float s2 = 0.f, s6 = 0.f;
#pragma unroll
            for (int m = 0; m < 8; ++m)
#pragma unroll
                for (int j = 0; j < 4; ++j) {
                    const float v = acck[m][n][j], v2 = v * v;
                    s2 += v2; s6 += v2 * v2 * v2;
                }
            s2 += __shfl_xor(s2, 16); s6 += __shfl_xor(s6, 16);
            s2 += __shfl_xor(s2, 32); s6 += __shfl_xor(s6, 32);
            fkn[n] = sqrtf(s2 / s6);
        }
#pragma unroll
        for (int m = 0; m < 8; ++m)
#pragma unroll
            for (int n = 0; n < 2; ++n)
#pragma unroll
                for (int j = 0; j < 4; ++j) {
                    const float v = acck[m][n][j];
                    acck[m][n][j] = v * v * v * fkn[n];
                }
        float ks4[4] = {0.f, 0.f, 0.f, 0.f};
#pragma unroll
        for (int n = 0; n < 2; ++n) {
            const int t = l & 15;
            const int rb = w * 8192 + t * 512;
#pragma unroll
            for (int m = 0; m < 8; ++m) {
                const int ad = rb + (((m * 16 + crow) * 4) ^ ((t & 7) << 4));
                *(f32x4*)(smem + ad) = acck[m][n];
            }
            asm volatile("s_waitcnt lgkmcnt(0)" ::: "memory");
#pragma unroll
            for (int j = 0; j < 8; ++j) {
                const int fid = j * 64 + l;
                const int row = fid >> 5;
                const int c4  = fid & 31;
                const int rb3 = w * 8192 + row * 512;
                const f32x4 v = *(f32x4*)(smem + rb3 + ((c4 * 16) ^ ((row & 7) << 4)));
                short4v kv;
#pragma unroll
                for (int i = 0; i < 4; ++i) {
                    ks4[i] += v[i];
                    kv[i] = (short)f2bf(v[i]);
                }
                *(short4v*)(kout + (tok0 + w * 32 + n * 16 + row) * 128 + c4 * 4) = kv;
            }
        }
#pragma unroll
        for (int i = 0; i < 4; ++i) ks4[i] += __shfl_xor(ks4[i], 32);
        if (l < 32) {
#pragma unroll
            for (int i = 0; i < 4; ++i) wpart[w][128 + (l & 31) * 4 + i] = ks4[i];
        }
    }

    __syncthreads();
    float* pblk = partial + blk * 257;
    if (tid < 128) {
        pblk[tid] = wpart[0][tid] + wpart[1][tid] + wpart[2][tid] + wpart[3][tid];
        pblk[128 + tid] = wpart[0][128 + tid] + wpart[1][128 + tid] +
                          wpart[2][128 + tid] + wpart[3][128 + tid];
    } else if (tid == 128) {
        pblk[256] = wpart[0][256] + wpart[1][256] + wpart[2][256] + wpart[3][256];
    }
}

// ---------------------------------------------------------------------------
// reduce partials -> G, kbar. grid 8, block 256. 128 tiles/batch.
// ---------------------------------------------------------------------------
__global__ __launch_bounds__(256) void reduce_kernel(
    const float* __restrict__ partial, float* __restrict__ G,
    float* __restrict__ kbar)
{
    const int b = blockIdx.x;
    const int tid = threadIdx.x;
    __shared__ float tmp[4];

    float ssa = (tid < 128) ? partial[(b * 128 + tid) * 257 + 256] : 0.f;
#pragma unroll
    for (int o = 32; o >= 1; o >>= 1) ssa += __shfl_xor(ssa, o);
    if ((tid & 63) == 0) tmp[tid >> 6] = ssa;
    __syncthreads();
    const float anorm = fmaxf(sqrtf(tmp[0] + tmp[1] + tmp[2] + tmp[3]), 1e-12f);
    const float inv_a = 1.f / anorm;

    if (tid < 128) {
        float g = 0.f;
        for (int t = 0; t < 128; ++t)
            g += partial[(b * 128 + t) * 257 + tid];
        G[b * 128 + tid] = g * inv_a;
    } else {
        const int c2 = tid - 128;
        float s = 0.f;
        for (int t = 0; t < 128; ++t)
            s += partial[(b * 128 + t) * 257 + 128 + c2];
        kbar[b * 128 + c2] = s * (1.f / 16384.f);
    }
}

// ---------------------------------------------------------------------------
// scramble: z + gating + cube-transpose. q and k both bf16.
// grid 2048, block 256.
// ---------------------------------------------------------------------------
__global__ __launch_bounds__(256) void scramble_kernel(
    const unsigned short* __restrict__ q, const unsigned short* __restrict__ k,
    const float* __restrict__ G, const float* __restrict__ kbar,
    float* __restrict__ out)
{
    __shared__ float u[64 * 129];
    const int tid  = threadIdx.x;
    const int bid  = blockIdx.x;
    const int half = bid & 1;
    const int r    = (bid >> 1) & 127;
    const int b    = bid >> 8;

    const int t  = tid >> 2;
    const int qt = tid & 3;
    const int tok   = r * 128 + half * 64 + t;
    const int gbase = (b * NN + tok) * CC + qt * 32;
    const int cb    = b * CC + qt * 32;

    float4 kb4[8], g4[8];
    float qf[32], kf[32];
#pragma unroll
    for (int j = 0; j < 8; ++j) {
        const short4v q4 = *(const short4v*)(q + gbase + j * 4);
        const short4v k4 = *(const short4v*)(k + gbase + j * 4);
#pragma unroll
        for (int i = 0; i < 4; ++i) {
            qf[j * 4 + i] = bf2f((unsigned short)q4[i]);
            kf[j * 4 + i] = bf2f((unsigned short)k4[i]);
        }
        kb4[j] = *(const float4*)(kbar + cb + j * 4);
        g4[j]  = *(const float4*)(G + cb + j * 4);
    }
    float dot0 = 0.f, dot1 = 0.f;
#pragma unroll
    for (int j = 0; j < 4; ++j) {
        dot0 += qf[j * 4] * kb4[j].x + qf[j * 4 + 1] * kb4[j].y +
                qf[j * 4 + 2] * kb4[j].z + qf[j * 4 + 3] * kb4[j].w;
        dot1 += qf[16 + j * 4] * kb4[j + 4].x + qf[16 + j * 4 + 1] * kb4[j + 4].y +
                qf[16 + j * 4 + 2] * kb4[j + 4].z + qf[16 + j * 4 + 3] * kb4[j + 4].w;
    }
    const float z0 = 1.f / (dot0 + 1e-6f);
    const float z1 = 1.f / (dot1 + 1e-6f);

    float* ut = u + t * 129 + qt * 32;
#pragma unroll
    for (int j = 0; j < 8; ++j) {
        const float zz = (j < 4) ? z0 : z1;
#pragma unroll
        for (int i = 0; i < 4; ++i) {
            const float gv = (i == 0) ? g4[j].x : (i == 1) ? g4[j].y : (i == 2) ? g4[j].z : g4[j].w;
            ut[j * 4 + i] = gv * kf[j * 4 + i] * zz;
        }
    }
    __syncthreads();

    const int obase = b * NN * CC + half * 64;
#pragma unroll
    for (int it = 0; it < 32; ++it) {
        const int idx = tid + it * 256;
        const int cc  = idx >> 6;
        const int ch  = idx & 63;
        out[obase + (cc * 128 + r) * CC + ch] = u[ch * 129 + cc];
    }
}

// ---------------------------------------------------------------------------
// convproj: fused depthwise 5x5 conv (bf16 k) + projection, in-place on out.
// Batch-per-XCD swizzle. grid 1024, block 256.
// ---------------------------------------------------------------------------
__global__ __launch_bounds__(256, 2) void convproj_kernel(
    float* __restrict__ out, const unsigned short* __restrict__ kbuf,
    const unsigned short* __restrict__ whi, const unsigned short* __restrict__ wlo,
    const float* __restrict__ bp, const float* __restrict__ dwc_w,
    const float* __restrict__ dwc_b)
{
    __shared__ __align__(16) char smem[65536];   // tile hi [0,32K), lo [32K,64K)
    __shared__ float wct[25][16];
    __shared__ float bi[16];

    const int tid  = threadIdx.x;
    const int bid0 = blockIdx.x;
    const int bid  = (bid0 & 7) * 128 + (bid0 >> 3);   // bijective XCD swizzle
    const int cc   = bid & 127;
    const int b    = bid >> 7;
    const int n0   = bid * 128;

    for (int i = tid; i < 400; i += 256)
        wct[i >> 4][i & 15] = dwc_w[(i & 15) * 25 + (i >> 4)];
    if (tid < 16) bi[tid] = dwc_b[tid];
    __syncthreads();

    const int l  = tid & 31;
    const int xg = tid >> 5;
    const int dbase = (l & 3) * 4;

    float4 acc[16];
#pragma unroll
    for (int i = 0; i < 16; ++i) acc[i] = make_float4(0.f, 0.f, 0.f, 0.f);

#pragma unroll
    for (int dy = 0; dy < 5; ++dy) {
        const int yy = cc + dy - 2;
        if (yy < 0 || yy > 127) continue;
        const unsigned short* rowb = kbuf + (b * NN + yy * 128) * CC + l * 4;
        float4 rowv[20];
#pragma unroll
        for (int xi = 0; xi < 20; ++xi) {
            const int xx = xg * 16 - 2 + xi;
            if (xx >= 0 && xx < 128) {
                const short4v kv4 = *(const short4v*)(rowb + xx * CC);
                rowv[xi] = make_float4(bf2f((unsigned short)kv4[0]),
                                       bf2f((unsigned short)kv4[1]),
                                       bf2f((unsigned short)kv4[2]),
                                       bf2f((unsigned short)kv4[3]));
            } else {
                rowv[xi] = make_float4(0.f, 0.f, 0.f, 0.f);
            }
        }
#pragma unroll
        for (int dx = 0; dx < 5; ++dx) {
            const float4 wv = *(const float4*)(&wct[dy * 5 + dx][dbase]);
#pragma unroll
            for (int i = 0; i < 16; ++i) {
                acc[i].x += wv.x * rowv[i + dx].x;
                acc[i].y += wv.y * rowv[i + dx].y;
                acc[i].z += wv.z * rowv[i + dx].z;
                acc[i].w += wv.w * rowv[i + dx].w;
            }
        }
    }

    const float4 b4 = *(const float4*)(&bi[dbase]);
#pragma unroll
    for (int i = 0; i < 16; ++i) {
        const int r = xg * 16 + i;
        const float4 pp = *(const float4*)(out + (n0 + r) * 128 + l * 4);
        float f[4] = {pp.x + acc[i].x + b4.x, pp.y + acc[i].y + b4.y,
                      pp.z + acc[i].z + b4.z, pp.w + acc[i].w + b4.w};
        short4v hv, lv;
#pragma unroll
        for (int j = 0; j < 4; ++j) {
            short h, lo2;
            split_trunc(f[j], h, lo2);
            hv[j] = h; lv[j] = lo2;
        }
        const int ad = r * 256 + (((l >> 1) * 16) ^ ((r & 7) << 4)) + (l & 1) * 8;
        *(short4v*)(smem + ad) = hv;
        *(short4v*)(smem + 32768 + ad) = lv;
    }
    __syncthreads();

    const int w  = tid >> 6;
    const int ll = tid & 63;
    bf16x8 xh[2][4], xl[2][4];
    {
        const int lg16 = (ll >> 4) * 16;
#pragma unroll
        for (int n = 0; n < 2; ++n) {
            const int r = w * 32 + n * 16 + (ll & 15);
            const int rb = r * 256;
            const int sw = (r & 7) << 4;
#pragma unroll
            for (int kt = 0; kt < 4; ++kt) {
                const int ad = rb + ((kt * 64 + lg16) ^ sw);
                xh[n][kt] = *(bf16x8*)(smem + ad);
                xl[n][kt] = *(bf16x8*)(smem + 32768 + ad);
            }
        }
    }
    const int crow = (ll >> 4) * 4;
    f32x4 pacc[8][2];
#pragma unroll
    for (int m = 0; m < 8; ++m)
#pragma unroll
        for (int n = 0; n < 2; ++n) pacc[m][n] = (f32x4)0.f;

#pragma unroll
    for (int m = 0; m < 8; ++m) {
        const int c = m * 16 + (ll & 15);
        bf16x8 ah[4], al[4];
#pragma unroll
        for (int kt = 0; kt < 4; ++kt) {
            const int off = 32768 + c * 128 + kt * 32 + (ll >> 4) * 8;
            ah[kt] = *(const bf16x8*)(whi + off);
            al[kt] = *(const bf16x8*)(wlo + off);
        }
#pragma unroll
        for (int n = 0; n < 2; ++n)
#pragma unroll
            for (int kt = 0; kt < 4; ++kt) {
                pacc[m][n] = __builtin_amdgcn_mfma_f32_16x16x32_bf16(ah[kt], xh[n][kt], pacc[m][n], 0, 0, 0);
                pacc[m][n] = __builtin_amdgcn_mfma_f32_16x16x32_bf16(ah[kt], xl[n][kt], pacc[m][n], 0, 0, 0);
                pacc[m][n] = __builtin_amdgcn_mfma_f32_16x16x32_bf16(al[kt], xh[n][kt], pacc[m][n], 0, 0, 0);
            }
    }

#pragma unroll
    for (int m = 0; m < 8; ++m) {
        const float4 bv = *(const float4*)(bp + m * 16 + crow);
        const float bb[4] = {bv.x, bv.y, bv.z, bv.w};
#pragma unroll
        for (int n = 0; n < 2; ++n)
#pragma unroll
            for (int j = 0; j < 4; ++j) pacc[m][n][j] += bb[j];
    }
    __syncthreads();
#pragma unroll
    for (int n = 0; n < 2; ++n) {
        const int t = n * 16 + (ll & 15);
        const int rb = w * 8192 + (t & 15) * 512 + ((t >= 16) ? 32768 : 0);
#pragma unroll
        for (int m = 0; m < 8; ++m) {
            const int ad = rb + (((m * 16 + crow) * 4) ^ ((t & 7) << 4));
            *(f32x4*)(smem + ad) = pacc[m][n];
        }
    }
    asm volatile("s_waitcnt lgkmcnt(0)" ::: "memory");
#pragma unroll
    for (int j = 0; j < 16; ++j) {
        const int fid = j * 64 + ll;
        const int row = fid >> 5;
        const int c4 = fid & 31;
        const int rb = w * 8192 + (row & 15) * 512 + ((row >= 16) ? 32768 : 0);
        const f32x4 v = *(f32x4*)(smem + rb + ((c4 * 16) ^ ((row & 7) << 4)));
        *(f32x4*)(out + (n0 + w * 32 + row) * 128 + c4 * 4) = v;
    }
}

// ---------------------------------------------------------------------------
extern "C" void kernel_launch(void* const* d_in, const int* in_sizes, int n_in,
                              void* d_out, int out_size, void* d_ws, size_t ws_size,
                              hipStream_t stream)
{
    const float* x       = (const float*)d_in[0];
    const float* Wq      = (const float*)d_in[1];
    const float* Wkv     = (const float*)d_in[2];
    const float* Wproj   = (const float*)d_in[3];
    const float* bproj   = (const float*)d_in[4];
    const float* w_g     = (const float*)d_in[5];
    const float* scale   = (const float*)d_in[6];
    const float* pos_enc = (const float*)d_in[7];
    const float* dwc_w   = (const float*)d_in[8];
    const float* dwc_b   = (const float*)d_in[9];
    float* out = (float*)d_out;

    char* ws = (char*)d_ws;
    unsigned short* qbuf = (unsigned short*)(ws);             // 33554432 B
    unsigned short* kbuf = (unsigned short*)(ws + 33554432);  // 33554432 B
    float* partial = (float*)(ws + 67108864);                 // 1024*257*4 = 1052672 B
    float* G       = (float*)(ws + 68161536);                 // 4096 B
    float* kbar    = (float*)(ws + 68165632);                 // 4096 B
    unsigned short* whi = (unsigned short*)(ws + 68169728);   // 98304 B
    unsigned short* wlo = (unsigned short*)(ws + 68268032);   // 98304 B
    float* sps     = (float*)(ws + 68366336);                 // 512 B

    wprep_kernel<<<dim3(49), dim3(256), 0, stream>>>(
        Wq, Wkv, Wproj, scale, whi, wlo, sps);
    qk_mfma_kernel<<<dim3(1024), dim3(256), 0, stream>>>(
        x, whi, wlo, w_g, sps, pos_enc, qbuf, kbuf, partial);
    reduce_kernel<<<dim3(8), dim3(256), 0, stream>>>(partial, G, kbar);
    scramble_kernel<<<dim3(2048), dim3(256), 0, stream>>>(
        qbuf, kbuf, G, kbar, out);
    convproj_kernel<<<dim3(1024), dim3(256), 0, stream>>>(
        out, kbuf, whi, wlo, bproj, dwc_w, dwc_b);
}

// Round 12
// 224.268 us; speedup vs baseline: 1.3188x; 1.0162x over previous
//
#include <hip/hip_runtime.h>
#include <hip/hip_bf16.h>

#define BB 8
#define NN 16384
#define CC 128

typedef __attribute__((ext_vector_type(8))) short bf16x8;
typedef __attribute__((ext_vector_type(4))) short short4v;
typedef __attribute__((ext_vector_type(4))) float f32x4;

__device__ __forceinline__ unsigned short f2bf(float f) {
    union { float f; unsigned u; } v; v.f = f;
    unsigned r = v.u + 0x7fffu + ((v.u >> 16) & 1u);
    return (unsigned short)(r >> 16);
}
__device__ __forceinline__ float bf2f(unsigned short h) {
    union { unsigned u; float f; } v; v.u = ((unsigned)h) << 16;
    return v.f;
}
// truncating hi/lo split: lo captures the residual, RNE on hi unnecessary
__device__ __forceinline__ void split_trunc(float f, short& hi, short& lo) {
    union { float f; unsigned u; } v; v.f = f;
    const unsigned short hu = (unsigned short)(v.u >> 16);
    union { unsigned u; float f; } hf; hf.u = ((unsigned)hu) << 16;
    union { float f; unsigned u; } r; r.f = f - hf.f;
    hi = (short)hu;
    lo = (short)(r.u >> 16);
}

// ---------------------------------------------------------------------------
// W prep: split Wq/Wkv/Wproj into bf16 hi/lo (blocks 0-47); block 48
// precomputes sps[c] = 1/softplus(scale[c]). grid 49, block 256.
// ---------------------------------------------------------------------------
__global__ __launch_bounds__(256) void wprep_kernel(
    const float* __restrict__ Wq, const float* __restrict__ Wkv,
    const float* __restrict__ Wp, const float* __restrict__ scale,
    unsigned short* __restrict__ whi, unsigned short* __restrict__ wlo,
    float* __restrict__ sps)
{
    const int bid = blockIdx.x;
    if (bid == 48) {
        if (threadIdx.x < 128)
            sps[threadIdx.x] = 1.f / log1pf(expf(scale[threadIdx.x]));
        return;
    }
    const int mat = bid >> 4;
    const float* src = (mat == 0) ? Wq : ((mat == 1) ? Wkv : Wp);
    const int off = (bid & 15) * 1024 + threadIdx.x * 4;
    const float4 v = *(const float4*)(src + off);
    float f[4] = {v.x, v.y, v.z, v.w};
    short4v hv, lv;
#pragma unroll
    for (int j = 0; j < 4; ++j) {
        short h, lo2;
        split_trunc(f[j], h, lo2);
        hv[j] = h; lv[j] = lo2;
    }
    *(short4v*)(whi + mat * 16384 + off) = hv;
    *(short4v*)(wlo + mat * 16384 + off) = lv;
}

// ---------------------------------------------------------------------------
// qk v7: R11 fused q+k MFMA structure, plus k additionally emitted in
// CHANNEL-MAJOR layout k_t[b*128+c][N] (32MB extra write) so the fused
// scramble+conv+proj kernel can synthesize the gated-u part inline and the
// scramble kernel (64MB write + 64MB re-read) is deleted.
// grid 1024, block 256 (4 waves x 32 tokens).
// ---------------------------------------------------------------------------
__global__ __launch_bounds__(256, 1) void qk_mfma_kernel(
    const float* __restrict__ x, const unsigned short* __restrict__ whi,
    const unsigned short* __restrict__ wlo, const float* __restrict__ w_g,
    const float* __restrict__ sps, const float* __restrict__ pos_enc,
    unsigned short* __restrict__ qout, unsigned short* __restrict__ kout,
    unsigned short* __restrict__ ktout, float* __restrict__ partial)
{
    __shared__ __align__(16) char smem[33792];   // q/k transpose (4x8KB) then k_t scatter [128][132]
    __shared__ float wpart[4][257];
    __shared__ float apl[128];

    const int tid  = threadIdx.x;
    const int w    = tid >> 6;
    const int l    = tid & 63;
    const int blk  = blockIdx.x;
    const int tok0 = blk * 128;
    const int tokb = (blk & 127) * 128;

    // ---- direct per-wave fragment loads: fp32 -> hi/lo bf16 in-register ----
    bf16x8 xh[2][4], xl[2][4];
#pragma unroll
    for (int n = 0; n < 2; ++n) {
        const int r = w * 32 + n * 16 + (l & 15);
        const float* rowp = x + (tok0 + r) * 128 + (l >> 4) * 8;
#pragma unroll
        for (int kt = 0; kt < 4; ++kt) {
            const f32x4 a = *(const f32x4*)(rowp + kt * 32);
            const f32x4 b = *(const f32x4*)(rowp + kt * 32 + 4);
            const float f[8] = {a[0], a[1], a[2], a[3], b[0], b[1], b[2], b[3]};
            bf16x8 hv, lv;
#pragma unroll
            for (int j = 0; j < 8; ++j) {
                short h, lo2;
                split_trunc(f[j], h, lo2);
                hv[j] = h; lv[j] = lo2;
            }
            xh[n][kt] = hv; xl[n][kt] = lv;
        }
    }

    const int crow = (l >> 4) * 4;
    f32x4 accq[8][2], acck[8][2];
#pragma unroll
    for (int m = 0; m < 8; ++m)
#pragma unroll
        for (int n = 0; n < 2; ++n) { accq[m][n] = (f32x4)0.f; acck[m][n] = (f32x4)0.f; }

    // =================== fused q+k MFMA loop ===================
#pragma unroll
    for (int m = 0; m < 8; ++m) {
        const int c = m * 16 + (l & 15);
        bf16x8 aqh[4], aql[4], akh[4], akl[4];
#pragma unroll
        for (int kt = 0; kt < 4; ++kt) {
            const int off = c * 128 + kt * 32 + (l >> 4) * 8;
            aqh[kt] = *(const bf16x8*)(whi + off);
            aql[kt] = *(const bf16x8*)(wlo + off);
            akh[kt] = *(const bf16x8*)(whi + 16384 + off);
            akl[kt] = *(const bf16x8*)(wlo + 16384 + off);
        }
#pragma unroll
        for (int n = 0; n < 2; ++n)
#pragma unroll
            for (int kt = 0; kt < 4; ++kt) {
                accq[m][n] = __builtin_amdgcn_mfma_f32_16x16x32_bf16(aqh[kt], xh[n][kt], accq[m][n], 0, 0, 0);
                acck[m][n] = __builtin_amdgcn_mfma_f32_16x16x32_bf16(akh[kt], xh[n][kt], acck[m][n], 0, 0, 0);
                accq[m][n] = __builtin_amdgcn_mfma_f32_16x16x32_bf16(aqh[kt], xl[n][kt], accq[m][n], 0, 0, 0);
                acck[m][n] = __builtin_amdgcn_mfma_f32_16x16x32_bf16(akh[kt], xl[n][kt], acck[m][n], 0, 0, 0);
                accq[m][n] = __builtin_amdgcn_mfma_f32_16x16x32_bf16(aql[kt], xh[n][kt], accq[m][n], 0, 0, 0);
                acck[m][n] = __builtin_amdgcn_mfma_f32_16x16x32_bf16(akl[kt], xh[n][kt], acck[m][n], 0, 0, 0);
            }
    }

    // ---- q epilogue ----
    {
#pragma unroll
        for (int m = 0; m < 8; ++m) {
            const float4 is4 = *(const float4*)(sps + m * 16 + crow);
            const float is[4] = {is4.x, is4.y, is4.z, is4.w};
#pragma unroll
            for (int n = 0; n < 2; ++n)
#pragma unroll
                for (int j = 0; j < 4; ++j)
                    accq[m][n][j] = (fmaxf(accq[m][n][j], 0.f) + 1e-6f) * is[j];
        }
        float fqn[2];
#pragma unroll
        for (int n = 0; n < 2; ++n) {
            float s2 = 0.f, s6 = 0.f;
#pragma unroll
            for (int m = 0; m < 8; ++m)
#pragma unroll
                for (int j = 0; j < 4; ++j) {
                    const float v = accq[m][n][j], v2 = v * v;
                    s2 += v2; s6 += v2 * v2 * v2;
                }
            s2 += __shfl_xor(s2, 16); s6 += __shfl_xor(s6, 16);
            s2 += __shfl_xor(s2, 32); s6 += __shfl_xor(s6, 32);
            fqn[n] = sqrtf(s2 / s6);
        }
#pragma unroll
        for (int m = 0; m < 8; ++m)
#pragma unroll
            for (int n = 0; n < 2; ++n)
#pragma unroll
                for (int j = 0; j < 4; ++j) {
                    const float v = accq[m][n][j];
                    accq[m][n][j] = v * v * v * fqn[n];
                }
        float d0 = 0.f, d1 = 0.f;
#pragma unroll
        for (int m = 0; m < 8; ++m) {
            const float4 wgv = *(const float4*)(w_g + m * 16 + crow);
#pragma unroll
            for (int j = 0; j < 4; ++j) {
                const float wg = (j == 0) ? wgv.x : (j == 1) ? wgv.y : (j == 2) ? wgv.z : wgv.w;
                d0 += accq[m][0][j] * wg;
                d1 += accq[m][1][j] * wg;
            }
        }
        d0 += __shfl_xor(d0, 16); d0 += __shfl_xor(d0, 32);
        d1 += __shfl_xor(d1, 16); d1 += __shfl_xor(d1, 32);
        const float ap0 = 0.25f * d0, ap1 = 0.25f * d1;

        float ssa = ap0 * ap0 + ap1 * ap1;
        ssa += __shfl_xor(ssa, 1); ssa += __shfl_xor(ssa, 2);
        ssa += __shfl_xor(ssa, 4); ssa += __shfl_xor(ssa, 8);
        if (l == 0) wpart[w][256] = ssa;
        if (l < 16) { apl[w * 32 + l] = ap0; apl[w * 32 + 16 + l] = ap1; }

        // transpose via wave-private 8KB, two 16-token sub-phases
        float g4[4] = {0.f, 0.f, 0.f, 0.f};
#pragma unroll
        for (int n = 0; n < 2; ++n) {
            const int t = l & 15;
            const int rb = w * 8192 + t * 512;
#pragma unroll
            for (int m = 0; m < 8; ++m) {
                const int ad = rb + (((m * 16 + crow) * 4) ^ ((t & 7) << 4));
                *(f32x4*)(smem + ad) = accq[m][n];
            }
            asm volatile("s_waitcnt lgkmcnt(0)" ::: "memory");
#pragma unroll
            for (int j = 0; j < 8; ++j) {
                const int fid = j * 64 + l;
                const int row = fid >> 5;
                const int c4  = fid & 31;
                const int rb3 = w * 8192 + row * 512;
                const f32x4 v = *(f32x4*)(smem + rb3 + ((c4 * 16) ^ ((row & 7) << 4)));
                const float apv = apl[w * 32 + n * 16 + row];
                short4v qv;
#pragma unroll
                for (int i = 0; i < 4; ++i) {
                    g4[i] += apv * v[i];
                    qv[i] = (short)f2bf(v[i]);
                }
                *(short4v*)(qout + (tok0 + w * 32 + n * 16 + row) * 128 + c4 * 4) = qv;
            }
        }
#pragma unroll
        for (int i = 0; i < 4; ++i) g4[i] += __shfl_xor(g4[i], 32);
        if (l < 32) {
#pragma unroll
            for (int i = 0; i < 4; ++i) wpart[w][(l & 31) * 4 + i] = g4[i];
        }
    }

    // ---- k epilogue (token-major kout + partials) ----
    {
#pragma unroll
        for (int m = 0; m < 8; ++m) {
            const float4 is4 = *(const float4*)(sps + m * 16 + crow);
            const float is[4] = {is4.x, is4.y, is4.z, is4.w};
#pragma unroll
            for (int n = 0; n < 2; ++n) {
                const int t = tokb + w * 32 + n * 16 + (l & 15);
                const float4 p = *(const float4*)(pos_enc + t * 128 + m * 16 + crow);
                const float pe[4] = {p.x, p.y, p.z, p.w};
#pragma unroll
                for (int j = 0; j < 4; ++j)
                    acck[m][n][j] = (fmaxf(acck[m][n][j] + pe[j], 0.f) + 1e-6f) * is[j];
            }
        }
        float fkn[2];
#pragma unroll
        for (int n = 0; n < 2; ++n) {
            float s2 = 0.f, s6 = 0.f;
#pragma unroll
            for (int m = 0; m < 8; ++m)
#pragma unroll
                for (int j = 0; j < 4; ++j) {
                    const float v = acck[m][n][j], v2 = v * v;
                    s2 += v2; s6 += v2 * v2 * v2;
                }
            s2 += __shfl_xor(s2, 16); s6 += __shfl_xor(s6, 16);
            s2 += __shfl_xor(s2, 32); s6 += __shfl_xor(s6, 32);
            fkn[n] = sqrtf(s2 / s6);
        }
#pragma unroll
        for (int m = 0; m < 8; ++m)
#pragma unroll
            for (int n = 0; n < 2; ++n)
#pragma unroll
                for (int j = 0; j < 4; ++j) {
                    const float v = acck[m][n][j];
                    acck[m][n][j] = v * v * v * fkn[n];
                }
        float ks4[4] = {0.f, 0.f, 0.f, 0.f};
#pragma unroll
        for (int n = 0; n < 2; ++n) {
            const int t = l & 15;
            const int rb = w * 8192 + t * 512;
#pragma unroll
            for (int m = 0; m < 8; ++m) {
                const int ad = rb + (((m * 16 + crow) * 4) ^ ((t & 7) << 4));
                *(f32x4*)(smem + ad) = acck[m][n];
            }
            asm volatile("s_waitcnt lgkmcnt(0)" ::: "memory");
#pragma unroll
            for (int j = 0; j < 8; ++j) {
                const int fid = j * 64 + l;
                const int row = fid >> 5;
                const int c4  = fid & 31;
                const int rb3 = w * 8192 + row * 512;
                const f32x4 v = *(f32x4*)(smem + rb3 + ((c4 * 16) ^ ((row & 7) << 4)));
                short4v kv;
#pragma unroll
                for (int i = 0; i < 4; ++i) {
                    ks4[i] += v[i];
                    kv[i] = (short)f2bf(v[i]);
                }
                *(short4v*)(kout + (tok0 + w * 32 + n * 16 + row) * 128 + c4 * 4) = kv;
            }
        }
#pragma unroll
        for (int i = 0; i < 4; ++i) ks4[i] += __shfl_xor(ks4[i], 32);
        if (l < 32) {
#pragma unroll
            for (int i = 0; i < 4; ++i) wpart[w][128 + (l & 31) * 4 + i] = ks4[i];
        }
    }

    // ---- additionally emit k_t (channel-major) via block LDS scatter ----
    __syncthreads();   // all waves done with their private smem regions
#pragma unroll
    for (int m = 0; m < 8; ++m)
#pragma unroll
        for (int n = 0; n < 2; ++n)
#pragma unroll
            for (int j = 0; j < 4; ++j) {
                const int ch = m * 16 + crow + j;
                const int tl = w * 32 + n * 16 + (l & 15);
                *(unsigned short*)(smem + ch * 264 + tl * 2) =
                    f2bf(acck[m][n][j]);
            }
    __syncthreads();
    {
        const int bb = blk >> 7;
        unsigned* ktp = (unsigned*)ktout;
#pragma unroll
        for (int it = 0; it < 32; ++it) {
            const int idx = it * 256 + tid;
            const int row = idx >> 6;        // channel
            const int col = idx & 63;        // dword (2 tokens)
            const unsigned v = *(unsigned*)(smem + row * 264 + col * 4);
            ktp[(size_t)(bb * 128 + row) * 8192 + (blk & 127) * 64 + col] = v;
        }
    }

    __syncthreads();
    float* pblk = partial + blk * 257;
    if (tid < 128) {
        pblk[tid] = wpart[0][tid] + wpart[1][tid] + wpart[2][tid] + wpart[3][tid];
        pblk[128 + tid] = wpart[0][128 + tid] + wpart[1][128 + tid] +
                          wpart[2][128 + tid] + wpart[3][128 + tid];
    } else if (tid == 128) {
        pblk[256] = wpart[0][256] + wpart[1][256] + wpart[2][256] + wpart[3][256];
    }
}

// ---------------------------------------------------------------------------
// reduce partials -> G, kbar. grid 8, block 256. 128 tiles/batch.
// ---------------------------------------------------------------------------
__global__ __launch_bounds__(256) void reduce_kernel(
    const float* __restrict__ partial, float* __restrict__ G,
    float* __restrict__ kbar)
{
    const int b = blockIdx.x;
    const int tid = threadIdx.x;
    __shared__ float tmp[4];

    float ssa = (tid < 128) ? partial[(b * 128 + tid) * 257 + 256] : 0.f;
#pragma unroll
    for (int o = 32; o >= 1; o >>= 1) ssa += __shfl_xor(ssa, o);
    if ((tid & 63) == 0) tmp[tid >> 6] = ssa;
    __syncthreads();
    const float anorm = fmaxf(sqrtf(tmp[0] + tmp[1] + tmp[2] + tmp[3]), 1e-12f);
    const float inv_a = 1.f / anorm;

    if (tid < 128) {
        float g = 0.f;
        for (int t = 0; t < 128; ++t)
            g += partial[(b * 128 + t) * 257 + tid];
        G[b * 128 + tid] = g * inv_a;
    } else {
        const int c2 = tid - 128;
        float s = 0.f;
        for (int t = 0; t < 128; ++t)
            s += partial[(b * 128 + t) * 257 + 128 + c2];
        kbar[b * 128 + c2] = s * (1.f / 16384.f);
    }
}

// ---------------------------------------------------------------------------
// z kernel: z[b, h, t] = 1/(q[t, h-band] . kbar[b, h-band] + 1e-6).
// grid 2048 (8 batches x 256 groups of 64 tokens), block 256 (4 thr/token).
// ---------------------------------------------------------------------------
__global__ __launch_bounds__(256) void z_kernel(
    const unsigned short* __restrict__ q, const float* __restrict__ kbar,
    float* __restrict__ z)
{
    const int bid = blockIdx.x;
    const int b   = bid >> 8;
    const int tg  = bid & 255;
    const int tid = threadIdx.x;
    const int t   = tid >> 2;
    const int qt  = tid & 3;
    const int tok = tg * 64 + t;

    const unsigned short* qp = q + ((size_t)b * NN + tok) * 128 + qt * 32;
    const float* kb = kbar + b * 128 + qt * 32;

    float dot0 = 0.f, dot1 = 0.f;
#pragma unroll
    for (int c = 0; c < 4; ++c) {
        const short4v q4a = *(const short4v*)(qp + c * 8);
        const short4v q4b = *(const short4v*)(qp + c * 8 + 4);
        const float4 k4a = *(const float4*)(kb + c * 8);
        const float4 k4b = *(const float4*)(kb + c * 8 + 4);
        float d = bf2f((unsigned short)q4a[0]) * k4a.x + bf2f((unsigned short)q4a[1]) * k4a.y +
                  bf2f((unsigned short)q4a[2]) * k4a.z + bf2f((unsigned short)q4a[3]) * k4a.w +
                  bf2f((unsigned short)q4b[0]) * k4b.x + bf2f((unsigned short)q4b[1]) * k4b.y +
                  bf2f((unsigned short)q4b[2]) * k4b.z + bf2f((unsigned short)q4b[3]) * k4b.w;
        if (c < 2) dot0 += d; else dot1 += d;
    }
    z[((size_t)b * 8 + qt * 2) * NN + tok]     = 1.f / (dot0 + 1e-6f);
    z[((size_t)b * 8 + qt * 2 + 1) * NN + tok] = 1.f / (dot1 + 1e-6f);
}

// ---------------------------------------------------------------------------
// scp: fused scramble(u inline) + depthwise 5x5 conv + projection.
// Block (b, cc): output rows n = cc*128 + r. u-part synthesized from
// k_t (channel cc row, coalesced) and z (head cc>>4 row, L3-resident) —
// `out` is now write-only. Conv phase identical to prior convproj (token-
// major kbuf). Batch-per-XCD swizzle. grid 1024, block 256.
// ---------------------------------------------------------------------------
__global__ __launch_bounds__(256, 2) void scp_kernel(
    float* __restrict__ out, const unsigned short* __restrict__ kbuf,
    const unsigned short* __restrict__ kt, const float* __restrict__ z,
    const float* __restrict__ G,
    const unsigned short* __restrict__ whi, const unsigned short* __restrict__ wlo,
    const float* __restrict__ bp, const float* __restrict__ dwc_w,
    const float* __restrict__ dwc_b)
{
    __shared__ __align__(16) char smem[65536];   // tile hi [0,32K), lo [32K,64K)
    __shared__ float wct[25][16];
    __shared__ float bi[16];
    __shared__ float Gs;

    const int tid  = threadIdx.x;
    const int bid0 = blockIdx.x;
    const int bid  = (bid0 & 7) * 128 + (bid0 >> 3);   // bijective XCD swizzle
    const int cc   = bid & 127;
    const int b    = bid >> 7;
    const int n0   = bid * 128;

    for (int i = tid; i < 400; i += 256)
        wct[i >> 4][i & 15] = dwc_w[(i & 15) * 25 + (i >> 4)];
    if (tid < 16) bi[tid] = dwc_b[tid];
    if (tid == 0) Gs = G[b * 128 + cc];
    __syncthreads();

    const int l  = tid & 31;
    const int xg = tid >> 5;
    const int dbase = (l & 3) * 4;

    float4 acc[16];
#pragma unroll
    for (int i = 0; i < 16; ++i) acc[i] = make_float4(0.f, 0.f, 0.f, 0.f);

#pragma unroll
    for (int dy = 0; dy < 5; ++dy) {
        const int yy = cc + dy - 2;
        if (yy < 0 || yy > 127) continue;
        const unsigned short* rowb = kbuf + (b * NN + yy * 128) * CC + l * 4;
        float4 rowv[20];
#pragma unroll
        for (int xi = 0; xi < 20; ++xi) {
            const int xx = xg * 16 - 2 + xi;
            if (xx >= 0 && xx < 128) {
                const short4v kv4 = *(const short4v*)(rowb + xx * CC);
                rowv[xi] = make_float4(bf2f((unsigned short)kv4[0]),
                                       bf2f((unsigned short)kv4[1]),
                                       bf2f((unsigned short)kv4[2]),
                                       bf2f((unsigned short)kv4[3]));
            } else {
                rowv[xi] = make_float4(0.f, 0.f, 0.f, 0.f);
            }
        }
#pragma unroll
        for (int dx = 0; dx < 5; ++dx) {
            const float4 wv = *(const float4*)(&wct[dy * 5 + dx][dbase]);
#pragma unroll
            for (int i = 0; i < 16; ++i) {
                acc[i].x += wv.x * rowv[i + dx].x;
                acc[i].y += wv.y * rowv[i + dx].y;
                acc[i].z += wv.z * rowv[i + dx].z;
                acc[i].w += wv.w * rowv[i + dx].w;
            }
        }
    }

    // ---- phase 2: u-part inline + conv + bias -> split bf16 into LDS ----
    const float Gcc = Gs;
    const unsigned short* kub = kt + ((size_t)b * 128 + cc) * NN;
    const float* zr = z + ((size_t)b * 8 + (cc >> 4)) * NN;
    const float4 b4 = *(const float4*)(&bi[dbase]);
#pragma unroll
    for (int i = 0; i < 16; ++i) {
        const int r = xg * 16 + i;
        const int toks = r * 128 + l * 4;   // token base for the 4 channels
        const short4v ku4 = *(const short4v*)(kub + toks);
        const float4 z4 = *(const float4*)(zr + toks);
        const float zz[4] = {z4.x, z4.y, z4.z, z4.w};
        float f[4];
        const float av[4] = {acc[i].x, acc[i].y, acc[i].z, acc[i].w};
        const float bv[4] = {b4.x, b4.y, b4.z, b4.w};
#pragma unroll
        for (int c = 0; c < 4; ++c)
            f[c] = Gcc * bf2f((unsigned short)ku4[c]) * zz[c] + av[c] + bv[c];
        short4v hv, lv;
#pragma unroll
        for (int j = 0; j < 4; ++j) {
            short h, lo2;
            split_trunc(f[j], h, lo2);
            hv[j] = h; lv[j] = lo2;
        }
        const int ad = r * 256 + (((l >> 1) * 16) ^ ((r & 7) << 4)) + (l & 1) * 8;
        *(short4v*)(smem + ad) = hv;
        *(short4v*)(smem + 32768 + ad) = lv;
    }
    __syncthreads();

    const int w  = tid >> 6;
    const int ll = tid & 63;
    bf16x8 xh[2][4], xl[2][4];
    {
        const int lg16 = (ll >> 4) * 16;
#pragma unroll
        for (int n = 0; n < 2; ++n) {
            const int r = w * 32 + n * 16 + (ll & 15);
            const int rb = r * 256;
            const int sw = (r & 7) << 4;
#pragma unroll
            for (int kt2 = 0; kt2 < 4; ++kt2) {
                const int ad = rb + ((kt2 * 64 + lg16) ^ sw);
                xh[n][kt2] = *(bf16x8*)(smem + ad);
                xl[n][kt2] = *(bf16x8*)(smem + 32768 + ad);
            }
        }
    }
    const int crow = (ll >> 4) * 4;
    f32x4 pacc[8][2];
#pragma unroll
    for (int m = 0; m < 8; ++m)
#pragma unroll
        for (int n = 0; n < 2; ++n) pacc[m][n] = (f32x4)0.f;

#pragma unroll
    for (int m = 0; m < 8; ++m) {
        const int c = m * 16 + (ll & 15);
        bf16x8 ah[4], al[4];
#pragma unroll
        for (int kt2 = 0; kt2 < 4; ++kt2) {
            const int off = 32768 + c * 128 + kt2 * 32 + (ll >> 4) * 8;
            ah[kt2] = *(const bf16x8*)(whi + off);
            al[kt2] = *(const bf16x8*)(wlo + off);
        }
#pragma unroll
        for (int n = 0; n < 2; ++n)
#pragma unroll
            for (int kt2 = 0; kt2 < 4; ++kt2) {
                pacc[m][n] = __builtin_amdgcn_mfma_f32_16x16x32_bf16(ah[kt2], xh[n][kt2], pacc[m][n], 0, 0, 0);
                pacc[m][n] = __builtin_amdgcn_mfma_f32_16x16x32_bf16(ah[kt2], xl[n][kt2], pacc[m][n], 0, 0, 0);
                pacc[m][n] = __builtin_amdgcn_mfma_f32_16x16x32_bf16(al[kt2], xh[n][kt2], pacc[m][n], 0, 0, 0);
            }
    }

#pragma unroll
    for (int m = 0; m < 8; ++m) {
        const float4 bv = *(const float4*)(bp + m * 16 + crow);
        const float bb[4] = {bv.x, bv.y, bv.z, bv.w};
#pragma unroll
        for (int n = 0; n < 2; ++n)
#pragma unroll
            for (int j = 0; j < 4; ++j) pacc[m][n][j] += bb[j];
    }
    __syncthreads();
#pragma unroll
    for (int n = 0; n < 2; ++n) {
        const int t = n * 16 + (ll & 15);
        const int rb = w * 8192 + (t & 15) * 512 + ((t >= 16) ? 32768 : 0);
#pragma unroll
        for (int m = 0; m < 8; ++m) {
            const int ad = rb + (((m * 16 + crow) * 4) ^ ((t & 7) << 4));
            *(f32x4*)(smem + ad) = pacc[m][n];
        }
    }
    asm volatile("s_waitcnt lgkmcnt(0)" ::: "memory");
#pragma unroll
    for (int j = 0; j < 16; ++j) {
        const int fid = j * 64 + ll;
        const int row = fid >> 5;
        const int c4 = fid & 31;
        const int rb = w * 8192 + (row & 15) * 512 + ((row >= 16) ? 32768 : 0);
        const f32x4 v = *(f32x4*)(smem + rb + ((c4 * 16) ^ ((row & 7) << 4)));
        *(f32x4*)(out + (n0 + w * 32 + row) * 128 + c4 * 4) = v;
    }
}

// ---------------------------------------------------------------------------
extern "C" void kernel_launch(void* const* d_in, const int* in_sizes, int n_in,
                              void* d_out, int out_size, void* d_ws, size_t ws_size,
                              hipStream_t stream)
{
    const float* x       = (const float*)d_in[0];
    const float* Wq      = (const float*)d_in[1];
    const float* Wkv     = (const float*)d_in[2];
    const float* Wproj   = (const float*)d_in[3];
    const float* bproj   = (const float*)d_in[4];
    const float* w_g     = (const float*)d_in[5];
    const float* scale   = (const float*)d_in[6];
    const float* pos_enc = (const float*)d_in[7];
    const float* dwc_w   = (const float*)d_in[8];
    const float* dwc_b   = (const float*)d_in[9];
    float* out = (float*)d_out;

    char* ws = (char*)d_ws;
    unsigned short* qbuf = (unsigned short*)(ws);             // 33554432 B
    unsigned short* kbuf = (unsigned short*)(ws + 33554432);  // 33554432 B
    unsigned short* ktbuf= (unsigned short*)(ws + 67108864);  // 33554432 B
    float* partial = (float*)(ws + 100663296);                // 1052672 B
    float* G       = (float*)(ws + 101715968);                // 4096 B
    float* kbar    = (float*)(ws + 101720064);                // 4096 B
    unsigned short* whi = (unsigned short*)(ws + 101724160);  // 98304 B
    unsigned short* wlo = (unsigned short*)(ws + 101822464);  // 98304 B
    float* sps     = (float*)(ws + 101920768);                // 512 B
    float* zbuf    = (float*)(ws + 101921280);                // 4194304 B

    wprep_kernel<<<dim3(49), dim3(256), 0, stream>>>(
        Wq, Wkv, Wproj, scale, whi, wlo, sps);
    qk_mfma_kernel<<<dim3(1024), dim3(256), 0, stream>>>(
        x, whi, wlo, w_g, sps, pos_enc, qbuf, kbuf, ktbuf, partial);
    reduce_kernel<<<dim3(8), dim3(256), 0, stream>>>(partial, G, kbar);
    z_kernel<<<dim3(2048), dim3(256), 0, stream>>>(qbuf, kbar, zbuf);
    scp_kernel<<<dim3(1024), dim3(256), 0, stream>>>(
        out, kbuf, ktbuf, zbuf, G, whi, wlo, bproj, dwc_w, dwc_b);
}